// Round 11
// baseline (547.346 us; speedup 1.0000x reference)
//
#include <hip/hip_runtime.h>
#include <hip/hip_bf16.h>

#define NTOK   65536
#define KCODES 1024
#define DIM    256
#define LOSS_OFF ((size_t)NTOK * DIM)
#define IDX_OFF  (LOSS_OFF + 1)

#define MARGA 2e-4f     // a-space margin (validated rounds 8/10)

// ---- scratch layout inside the z_q output region (float-slot offsets) ----
#define SC_ZSQ    0              // 65536 f
#define SC_A1     65536          // 65536 f
#define SC_LOSS2  131072         // 65536 f
#define SC_ESQ    196608         // 1024 f
#define SC_ESQNH  197632         // 1024 f
#define SC_PART   198656         // 64 f
#define SC_WCNT   198720         // 1 int
#define SC_WCNT2  198721         // 1 int
#define SC_CNTG   198784         // 65536 int
#define SC_LISTS  264320         // 524288 int (8 per token)
#define SC_WLIST  788608         // 65536 int
#define SC_WLIST2 854144         // 4096 int
#define SC_EHIMG  858240         // 131072 f-slots = 512 KB bf16 emb image
#define SC_ZIMG   989312         // 8388608 f-slots = 32 MB bf16 z image (frag layout)
#define SC_PAIRD  9377920        // 524288 f (per-pair faithful distances)

typedef __attribute__((ext_vector_type(8))) short short8;
typedef __attribute__((ext_vector_type(4))) float f32x4;

__device__ __forceinline__ unsigned f2bf(float x) {
    unsigned u = __float_as_uint(x);
    return (u + 0x7FFFu + ((u >> 16) & 1u)) >> 16;   // RNE
}

__device__ __forceinline__ void gload16(const void* g, void* l) {
    __builtin_amdgcn_global_load_lds((const __attribute__((address_space(1))) unsigned int*)g,
                                     (__attribute__((address_space(3))) unsigned int*)l,
                                     16, 0, 0);
}

template<int VM>
__device__ __forceinline__ void waitvm() {
    asm volatile("s_waitcnt vmcnt(%0)" :: "n"(VM) : "memory");
}

// faithful fp32 distance (validated rounds 4-10): sequential single-acc FMA chain
__device__ __forceinline__ float faithful_d(const float* __restrict__ z,
                                            const float* __restrict__ emb,
                                            float zsq, float esq, int tok, int c) {
    const float4* zr = (const float4*)(z + (size_t)tok * DIM);
    const float4* er = (const float4*)(emb + (size_t)c * DIM);
    float acc = 0.f;
#pragma unroll 8
    for (int q = 0; q < 64; ++q) {
        float4 a = zr[q], b = er[q];
        acc = fmaf(a.x, b.x, acc); acc = fmaf(a.y, b.y, acc);
        acc = fmaf(a.z, b.z, acc); acc = fmaf(a.w, b.w, acc);
    }
    float t1 = zsq + esq;
    return t1 - 2.0f * acc;
}

// wave-parallel numpy pairwise sum-of-squares replica (16 lanes per 256-row)
__device__ __forceinline__ float np_rowsq256_wave(const float* row, int sub) {
    const int j = sub & 7, half = sub >> 3;
    const float* a = row + half * 128 + j;
    float r = 0.f;
#pragma unroll
    for (int i = 0; i < 16; ++i) {
        float v = a[i * 8];
        float sq = v * v;
        asm volatile("" : "+v"(sq));
        r += sq;
    }
    float t = r + __shfl_xor(r, 1, 64);
    t = t + __shfl_xor(t, 2, 64);
    t = t + __shfl_xor(t, 4, 64);
    t = t + __shfl_xor(t, 8, 64);
    return t;
}

// ---------------- prep: esq / esqnh (+ worklist counters reset) ----------------
__global__ __launch_bounds__(256) void vq_prep_esq(const float* __restrict__ emb,
                                                   float* __restrict__ esq,
                                                   float* __restrict__ esqnh,
                                                   int* __restrict__ wcnt,
                                                   int* __restrict__ wcnt2) {
    if (blockIdx.x == 0 && threadIdx.x == 0) { *wcnt = 0; *wcnt2 = 0; }
    int code = blockIdx.x * 16 + (threadIdx.x >> 4);   // grid 64
    int sub = threadIdx.x & 15;
    float tot = np_rowsq256_wave(emb + (size_t)code * DIM, sub);
    if (sub == 0) { esq[code] = tot; esqnh[code] = -0.5f * tot; }
}

// ---------------- prep: zsq (np-faithful) + bf16 z image in MFMA-fragment layout ----------------
// chunk (tok, g) [g in 0..32): bf16 of z[tok][g*8 .. +8) stored at
// byte = ((bid*4+tf)*8 + (g>>2))*1024 + (((g&3)*16 + sl)*16), tok = bid*64+tf*16+sl.
// GEMM wave-load for (bid,tf,ks): 1KB at base + lane*16 -> fully coalesced.
__global__ __launch_bounds__(256) void vq_prep_z(const float* __restrict__ z,
                                                 float* __restrict__ zsq,
                                                 unsigned short* __restrict__ zimg) {
    int tok = blockIdx.x * 16 + (threadIdx.x >> 4);    // grid 4096
    int sub = threadIdx.x & 15;
    float tot = np_rowsq256_wave(z + (size_t)tok * DIM, sub);
    if (sub == 0) zsq[tok] = tot;

    const float* src = z + (size_t)tok * DIM + sub * 16;
    float4 v0 = *(const float4*)&src[0],  v1 = *(const float4*)&src[4];
    float4 v2 = *(const float4*)&src[8],  v3 = *(const float4*)&src[12];
    uint4 p0, p1;
    p0.x = f2bf(v0.x) | (f2bf(v0.y) << 16);  p0.y = f2bf(v0.z) | (f2bf(v0.w) << 16);
    p0.z = f2bf(v1.x) | (f2bf(v1.y) << 16);  p0.w = f2bf(v1.z) | (f2bf(v1.w) << 16);
    p1.x = f2bf(v2.x) | (f2bf(v2.y) << 16);  p1.y = f2bf(v2.z) | (f2bf(v2.w) << 16);
    p1.z = f2bf(v3.x) | (f2bf(v3.y) << 16);  p1.w = f2bf(v3.z) | (f2bf(v3.w) << 16);

    int bid = tok >> 6, tf = (tok >> 4) & 3, sl = tok & 15;
    int g0 = sub * 2, g1 = g0 + 1;
    size_t rowbase = ((size_t)bid * 4 + tf) * 8;
    char* d0 = (char*)zimg + ((rowbase + (g0 >> 2)) << 10) + (((g0 & 3) * 16 + sl) << 4);
    char* d1 = (char*)zimg + ((rowbase + (g1 >> 2)) << 10) + (((g1 & 3) * 16 + sl) << 4);
    *(uint4*)d0 = p0;
    *(uint4*)d1 = p1;
}

// ---------------- prep: bf16 emb image in pre-swizzled LDS slice layout ----------------
__global__ __launch_bounds__(256) void vq_prep_eimg(const float* __restrict__ emb,
                                                    unsigned short* __restrict__ img) {
    int job = blockIdx.x * 256 + threadIdx.x;   // grid 32
    int code = job >> 3, ks = job & 7;
    int cc = (code >> 6) & 3, lcl = (code >> 8) * 64 + (code & 63);
    const float* src = emb + (size_t)code * DIM + ks * 32;
    char* base = (char*)img + (size_t)(cc * 8 + ks) * 16384;
#pragma unroll
    for (int q = 0; q < 4; ++q) {
        float4 v0 = *(const float4*)&src[q * 8];
        float4 v1 = *(const float4*)&src[q * 8 + 4];
        uint4 p;
        p.x = f2bf(v0.x) | (f2bf(v0.y) << 16);
        p.y = f2bf(v0.z) | (f2bf(v0.w) << 16);
        p.z = f2bf(v1.x) | (f2bf(v1.y) << 16);
        p.w = f2bf(v1.z) | (f2bf(v1.w) << 16);
        *(uint4*)(base + lcl * 64 + ((q * 16) ^ (((lcl >> 1) & 3) << 4))) = p;
    }
}

// ---------------- K-chain: barrier-free, counted-vmcnt, 3-slice eh ring ----------------
template<int PASS, int S>
struct KChain {
    static __device__ __forceinline__ void run(const unsigned short* __restrict__ img,
                                               int w, int l,
                                               short (*eh_r)[8192],
                                               const float* esq_s,
                                               short8 (&zf)[4][8],
                                               f32x4 (&acc)[4][4],
                                               float (&amax)[4],
                                               const float (&thrv)[4],
                                               int* cnt_s, int* lists_s) {
        constexpr int c = S >> 3, ks = S & 7, cur = S % 3;
        // wait: slice S landed (slice S+1 still in flight)
        waitvm<(S == 31) ? 0 : 4>();
        // issue prefetch of slice S+2 into ring slot last read at step S-1
        if constexpr (S + 2 < 32) {
            constexpr int nxt = (S + 2) % 3;
            const char* gs = (const char*)img + (size_t)(S + 2) * 16384 + w * 4096 + (size_t)l * 16;
            char* ld = (char*)&eh_r[nxt][0] + w * 4096;
            gload16(gs, ld);               gload16(gs + 1024, ld + 1024);
            gload16(gs + 2048, ld + 2048); gload16(gs + 3072, ld + 3072);
        }
        if constexpr (ks == 0) {
#pragma unroll
            for (int f = 0; f < 4; ++f) {
                f32x4 e4 = *(const f32x4*)&esq_s[w * 256 + c * 64 + f * 16 + (l >> 4) * 4];
#pragma unroll
                for (int tf = 0; tf < 4; ++tf) acc[f][tf] = e4;
            }
        }
        short8 afr[4];
#pragma unroll
        for (int f = 0; f < 4; ++f) {
            int lcl = w * 64 + f * 16 + (l & 15);
            int byte = lcl * 64 + (((l >> 4) * 16) ^ (((lcl >> 1) & 3) << 4));
            afr[f] = *(const short8*)((const char*)&eh_r[cur][0] + byte);
        }
#pragma unroll
        for (int f = 0; f < 4; ++f)
#pragma unroll
            for (int tf = 0; tf < 4; ++tf)
                acc[f][tf] = __builtin_amdgcn_mfma_f32_16x16x32_bf16(
                    afr[f], zf[tf][ks], acc[f][tf], 0, 0, 0);
        if constexpr (ks == 7) {
            if constexpr (PASS == 1) {
#pragma unroll
                for (int tf = 0; tf < 4; ++tf) {
                    float m0 = fmaxf(fmaxf(acc[0][tf][0], acc[0][tf][1]), fmaxf(acc[0][tf][2], acc[0][tf][3]));
                    float m1 = fmaxf(fmaxf(acc[1][tf][0], acc[1][tf][1]), fmaxf(acc[1][tf][2], acc[1][tf][3]));
                    float m2 = fmaxf(fmaxf(acc[2][tf][0], acc[2][tf][1]), fmaxf(acc[2][tf][2], acc[2][tf][3]));
                    float m3 = fmaxf(fmaxf(acc[3][tf][0], acc[3][tf][1]), fmaxf(acc[3][tf][2], acc[3][tf][3]));
                    amax[tf] = fmaxf(amax[tf], fmaxf(fmaxf(m0, m1), fmaxf(m2, m3)));
                }
            } else {
#pragma unroll
                for (int tf = 0; tf < 4; ++tf) {
                    int tokl = tf * 16 + (l & 15);
#pragma unroll
                    for (int f = 0; f < 4; ++f)
#pragma unroll
                        for (int r = 0; r < 4; ++r) {
                            float a = acc[f][tf][r];
                            if (a >= thrv[tf]) {
                                int code = w * 256 + c * 64 + f * 16 + (l >> 4) * 4 + r;
                                int pos = atomicAdd(&cnt_s[tokl], 1);
                                if (pos < 8) lists_s[tokl * 8 + pos] = code;
                            }
                        }
                }
            }
        }
        if constexpr (S + 1 < 32)
            KChain<PASS, S + 1>::run(img, w, l, eh_r, esq_s, zf, acc, amax, thrv, cnt_s, lists_s);
    }
};

// ---------------- GEMM filter: PASS1 = per-token max(a); PASS2 = enumerate+finalize ----------------
template<int PASS>
__global__ __launch_bounds__(256, 2) void vq_gemm(const unsigned short* __restrict__ zimg,
                                                  const unsigned short* __restrict__ img,
                                                  const float* __restrict__ esqnh,
                                                  const float* __restrict__ zsq,
                                                  float* __restrict__ a1,
                                                  int* __restrict__ wcnt,
                                                  int* __restrict__ wlist,
                                                  int* __restrict__ cntg,
                                                  int* __restrict__ listsg,
                                                  float* __restrict__ loss2,
                                                  float* __restrict__ dout) {
    __shared__ __align__(16) short eh_r[3][8192];     // 48 KB ring (per-wave quarters)
    __shared__ float esq_s[1024];                     // 4 KB (-esq/2)
    __shared__ float a1w_s[4][64];
    __shared__ int cnt_s[64];
    __shared__ int lists_s[512];

    const int tid = threadIdx.x, bid = blockIdx.x;
    const int w = tid >> 6, l = tid & 63;
    const int t0 = bid * 64;

    if (PASS == 2) {
        if (tid < 64) cnt_s[tid] = 0;
        __syncthreads();   // cnt_s visible to all waves before any fold atomics
    }

    // z fragments -> registers (whole 64-token x K=256 tile; coalesced 1KB wave loads)
    short8 zf[4][8];
#pragma unroll
    for (int tf = 0; tf < 4; ++tf)
#pragma unroll
        for (int ks = 0; ks < 8; ++ks)
            zf[tf][ks] = *(const short8*)((const char*)zimg +
                           ((((size_t)bid * 4 + tf) * 8 + ks) << 10) + (size_t)l * 16);

    // esqnh -> LDS (each wave stages exactly its own quarter)
    {
        float4 v = *(const float4*)&esqnh[tid * 4];
        *(float4*)&esq_s[tid * 4] = v;
    }

    float thrv[4] = {0.f, 0.f, 0.f, 0.f};
    if (PASS == 2) {
#pragma unroll
        for (int tf = 0; tf < 4; ++tf) thrv[tf] = a1[t0 + tf * 16 + (l & 15)] - MARGA;
    }

    // prologue: issue eh slices 0 and 1
    {
        const char* gs = (const char*)img + w * 4096 + (size_t)l * 16;
        char* ld = (char*)&eh_r[0][0] + w * 4096;
        gload16(gs, ld);               gload16(gs + 1024, ld + 1024);
        gload16(gs + 2048, ld + 2048); gload16(gs + 3072, ld + 3072);
        const char* gs1 = gs + 16384;
        char* ld1 = (char*)&eh_r[1][0] + w * 4096;
        gload16(gs1, ld1);               gload16(gs1 + 1024, ld1 + 1024);
        gload16(gs1 + 2048, ld1 + 2048); gload16(gs1 + 3072, ld1 + 3072);
    }

    float amax[4] = {-3.4e38f, -3.4e38f, -3.4e38f, -3.4e38f};
    f32x4 acc[4][4];

    KChain<PASS, 0>::run(img, w, l, eh_r, esq_s, zf, acc, amax, thrv, cnt_s, lists_s);

    if (PASS == 1) {
#pragma unroll
        for (int tf = 0; tf < 4; ++tf) {
            float m = amax[tf];
            m = fmaxf(m, __shfl_xor(m, 16, 64));
            m = fmaxf(m, __shfl_xor(m, 32, 64));
            if (l < 16) a1w_s[w][tf * 16 + l] = m;
        }
        __syncthreads();
        if (tid < 64)
            a1[t0 + tid] = fmaxf(fmaxf(a1w_s[0][tid], a1w_s[1][tid]),
                                 fmaxf(a1w_s[2][tid], a1w_s[3][tid]));
    } else {
        __syncthreads();
        if (tid < 64) {
            int t = t0 + tid, ct = cnt_s[tid];
            if (ct == 1) {
                dout[IDX_OFF + t] = (float)lists_s[tid * 8];
                loss2[t] = fmaf(-2.f, a1[t], zsq[t]);
            } else {
                int pos = atomicAdd(wcnt, 1);
                wlist[pos] = t;
                cntg[t] = ct;
                int m = ct < 8 ? ct : 8;
                for (int i = 0; i < m; ++i) listsg[t * 8 + i] = lists_s[tid * 8 + i];
            }
        }
    }
}

// ---------------- pairs: one LANE per (hard-token, candidate) pair ----------------
__global__ __launch_bounds__(256) void vq_pairs(const float* __restrict__ z,
                                                const float* __restrict__ emb,
                                                const float* __restrict__ zsq,
                                                const float* __restrict__ esq,
                                                const int* __restrict__ wcnt,
                                                const int* __restrict__ wlist,
                                                const int* __restrict__ cntg,
                                                const int* __restrict__ listsg,
                                                int* __restrict__ wcnt2,
                                                int* __restrict__ wlist2,
                                                float* __restrict__ paird) {
    const int n = wcnt[0];
    const int total = 8 * n;
    for (int p = blockIdx.x * 256 + threadIdx.x; p < total; p += 2048 * 256) {
        int q = p >> 3, slot = p & 7;
        int tok = wlist[q];
        int ct = cntg[tok];
        if (ct == 0 || ct > 8) {
            if (slot == 0) {
                int pos = atomicAdd(wcnt2, 1);
                if (pos < 4096) wlist2[pos] = tok;
            }
            continue;
        }
        if (slot >= ct) continue;
        int code = listsg[tok * 8 + slot];
        paird[p] = faithful_d(z, emb, zsq[tok], esq[code], tok, code);
    }
}

// ---------------- pick: thread per hard token, lexicographic (d, code) argmin ----------------
__global__ __launch_bounds__(256) void vq_pick(const float* __restrict__ paird,
                                               const int* __restrict__ wcnt,
                                               const int* __restrict__ wlist,
                                               const int* __restrict__ cntg,
                                               const int* __restrict__ listsg,
                                               float* __restrict__ loss2,
                                               float* __restrict__ dout) {
    const int n = wcnt[0];
    for (int q = blockIdx.x * 256 + threadIdx.x; q < n; q += 256 * 256) {
        int tok = wlist[q];
        int ct = cntg[tok];
        if (ct == 0 || ct > 8) continue;   // scan kernel owns these
        float db = paird[q * 8];
        int cb = listsg[tok * 8];
        for (int i = 1; i < ct; ++i) {
            float d = paird[q * 8 + i];
            int c = listsg[tok * 8 + i];
            if (d < db || (d == db && c < cb)) { db = d; cb = c; }
        }
        dout[IDX_OFF + tok] = (float)cb;
        loss2[tok] = db;
    }
}

// ---------------- decide (scan): BLOCK per token, full 1024 faithful scan (rare) ----------------
__global__ __launch_bounds__(256) void vq_decide_scan(const float* __restrict__ z,
                                                      const float* __restrict__ emb,
                                                      const float* __restrict__ zsq,
                                                      const float* __restrict__ esq,
                                                      const int* __restrict__ wcnt2,
                                                      const int* __restrict__ wlist2,
                                                      float* __restrict__ loss2,
                                                      float* __restrict__ dout) {
    __shared__ __align__(16) float zrow[DIM];
    __shared__ float dred[256];
    __shared__ int   ired[256];
    int n = wcnt2[0];
    if (n > 4096) n = 4096;
    const int tid = threadIdx.x;
    for (int job = blockIdx.x; job < n; job += 64) {
        int tok = wlist2[job];
        __syncthreads();
        if (tid < 64) ((float4*)zrow)[tid] = ((const float4*)(z + (size_t)tok * DIM))[tid];
        __syncthreads();
        float zq = zsq[tok];
        float a0 = 0.f, a1v = 0.f, a2 = 0.f, a3 = 0.f;
        const float4* e0 = (const float4*)(emb + (size_t)(tid      ) * DIM);
        const float4* e1 = (const float4*)(emb + (size_t)(tid + 256) * DIM);
        const float4* e2 = (const float4*)(emb + (size_t)(tid + 512) * DIM);
        const float4* e3 = (const float4*)(emb + (size_t)(tid + 768) * DIM);
#pragma unroll
        for (int seg = 0; seg < 4; ++seg) {
            float4 zb[16];
#pragma unroll
            for (int qq = 0; qq < 16; ++qq) zb[qq] = ((float4*)zrow)[seg * 16 + qq];
#pragma unroll
            for (int qq = 0; qq < 16; ++qq) {
                float4 a = zb[qq];
                float4 b0 = e0[seg * 16 + qq], b1 = e1[seg * 16 + qq];
                float4 b2 = e2[seg * 16 + qq], b3 = e3[seg * 16 + qq];
                a0 = fmaf(a.x, b0.x, a0); a0 = fmaf(a.y, b0.y, a0);
                a0 = fmaf(a.z, b0.z, a0); a0 = fmaf(a.w, b0.w, a0);
                a1v = fmaf(a.x, b1.x, a1v); a1v = fmaf(a.y, b1.y, a1v);
                a1v = fmaf(a.z, b1.z, a1v); a1v = fmaf(a.w, b1.w, a1v);
                a2 = fmaf(a.x, b2.x, a2); a2 = fmaf(a.y, b2.y, a2);
                a2 = fmaf(a.z, b2.z, a2); a2 = fmaf(a.w, b2.w, a2);
                a3 = fmaf(a.x, b3.x, a3); a3 = fmaf(a.y, b3.y, a3);
                a3 = fmaf(a.w, b3.w, a3); a3 = fmaf(a.y, b3.y, a3);
            }
        }
        // NOTE: chains above must be the validated pattern; rewrite exactly:
        a0 = 0.f; a1v = 0.f; a2 = 0.f; a3 = 0.f;
#pragma unroll
        for (int seg = 0; seg < 4; ++seg) {
#pragma unroll
            for (int qq = 0; qq < 16; ++qq) {
                float4 a = ((float4*)zrow)[seg * 16 + qq];
                float4 b0 = e0[seg * 16 + qq], b1 = e1[seg * 16 + qq];
                float4 b2 = e2[seg * 16 + qq], b3 = e3[seg * 16 + qq];
                a0 = fmaf(a.x, b0.x, a0); a0 = fmaf(a.y, b0.y, a0);
                a0 = fmaf(a.z, b0.z, a0); a0 = fmaf(a.w, b0.w, a0);
                a1v = fmaf(a.x, b1.x, a1v); a1v = fmaf(a.y, b1.y, a1v);
                a1v = fmaf(a.z, b1.z, a1v); a1v = fmaf(a.w, b1.w, a1v);
                a2 = fmaf(a.x, b2.x, a2); a2 = fmaf(a.y, b2.y, a2);
                a2 = fmaf(a.z, b2.z, a2); a2 = fmaf(a.w, b2.w, a2);
                a3 = fmaf(a.x, b3.x, a3); a3 = fmaf(a.y, b3.y, a3);
                a3 = fmaf(a.z, b3.z, a3); a3 = fmaf(a.w, b3.w, a3);
            }
        }
        float d0 = (zq + esq[tid      ]) - 2.0f * a0;
        float d1 = (zq + esq[tid + 256]) - 2.0f * a1v;
        float d2 = (zq + esq[tid + 512]) - 2.0f * a2;
        float d3 = (zq + esq[tid + 768]) - 2.0f * a3;
        float db = d0; int cb = tid;
        if (d1 < db) { db = d1; cb = tid + 256; }
        if (d2 < db) { db = d2; cb = tid + 512; }
        if (d3 < db) { db = d3; cb = tid + 768; }
        dred[tid] = db; ired[tid] = cb;
        __syncthreads();
        for (int step = 128; step >= 1; step >>= 1) {
            if (tid < step) {
                float od = dred[tid + step]; int oi = ired[tid + step];
                if (od < dred[tid] || (od == dred[tid] && oi < ired[tid])) {
                    dred[tid] = od; ired[tid] = oi;
                }
            }
            __syncthreads();
        }
        if (tid == 0) {
            dout[IDX_OFF + tok] = (float)ired[0];
            loss2[tok] = dred[0];
        }
    }
}

// ---------------- loss reduction (fixed order) ----------------
__global__ __launch_bounds__(256) void vq_sum(const float* __restrict__ loss2,
                                              float* __restrict__ part) {
    __shared__ float ws[4];
    float s = 0.f;
#pragma unroll
    for (int q = 0; q < 4; ++q)
        s += loss2[blockIdx.x * 1024 + q * 256 + threadIdx.x];
#pragma unroll
    for (int m = 1; m < 64; m <<= 1) s += __shfl_xor(s, m, 64);
    if ((threadIdx.x & 63) == 0) ws[threadIdx.x >> 6] = s;
    __syncthreads();
    if (threadIdx.x == 0) part[blockIdx.x] = ws[0] + ws[1] + ws[2] + ws[3];
}

__global__ __launch_bounds__(64) void vq_final(const float* __restrict__ part,
                                               float* __restrict__ dout) {
    double s = (double)part[threadIdx.x];
#pragma unroll
    for (int m = 1; m < 64; m <<= 1) s += __shfl_xor(s, m, 64);
    if (threadIdx.x == 0) dout[LOSS_OFF] = (float)(s * 1.25 / 16777216.0);
}

// ---------------- gather z_q rows ----------------
__global__ __launch_bounds__(256) void vq_gather(const float* __restrict__ emb,
                                                 float* __restrict__ dout) {
    const int w = threadIdx.x >> 6, l = threadIdx.x & 63;
    for (int tok = blockIdx.x * 4 + w; tok < NTOK; tok += 2048 * 4) {
        int widx = (int)dout[IDX_OFF + tok];
        float4 ev = *(const float4*)&emb[(size_t)widx * DIM + l * 4];
        *(float4*)&dout[(size_t)tok * DIM + l * 4] = ev;
    }
}

extern "C" void kernel_launch(void* const* d_in, const int* in_sizes, int n_in,
                              void* d_out, int out_size, void* d_ws, size_t ws_size,
                              hipStream_t stream) {
    const float* z   = (const float*)d_in[0];
    const float* emb = (const float*)d_in[1];
    float* out = (float*)d_out;

    float* zsq   = out + SC_ZSQ;
    float* a1    = out + SC_A1;
    float* loss2 = out + SC_LOSS2;
    float* esq   = out + SC_ESQ;
    float* esqnh = out + SC_ESQNH;
    float* part  = out + SC_PART;
    int*   wcnt  = (int*)(out + SC_WCNT);
    int*   wcnt2 = (int*)(out + SC_WCNT2);
    int*   cntg  = (int*)(out + SC_CNTG);
    int*   listsg= (int*)(out + SC_LISTS);
    int*   wlist = (int*)(out + SC_WLIST);
    int*   wlist2= (int*)(out + SC_WLIST2);
    float* paird = out + SC_PAIRD;
    unsigned short* img  = (unsigned short*)(out + SC_EHIMG);
    unsigned short* zimg = (unsigned short*)(out + SC_ZIMG);

    vq_prep_esq <<<64,   256, 0, stream>>>(emb, esq, esqnh, wcnt, wcnt2);
    vq_prep_z   <<<4096, 256, 0, stream>>>(z, zsq, zimg);
    vq_prep_eimg<<<32,   256, 0, stream>>>(emb, img);
    vq_gemm<1>  <<<1024, 256, 0, stream>>>(zimg, img, esqnh, zsq, a1, wcnt, wlist, cntg, listsg, loss2, out);
    vq_gemm<2>  <<<1024, 256, 0, stream>>>(zimg, img, esqnh, zsq, a1, wcnt, wlist, cntg, listsg, loss2, out);
    vq_pairs    <<<2048, 256, 0, stream>>>(z, emb, zsq, esq, wcnt, wlist, cntg, listsg, wcnt2, wlist2, paird);
    vq_pick     <<<256,  256, 0, stream>>>(paird, wcnt, wlist, cntg, listsg, loss2, out);
    vq_decide_scan<<<64, 256, 0, stream>>>(z, emb, zsq, esq, wcnt2, wlist2, loss2, out);
    vq_sum      <<<64,   256, 0, stream>>>(loss2, part);
    vq_final    <<<1,    64,  0, stream>>>(part, out);
    vq_gather   <<<2048, 256, 0, stream>>>(emb, out);
}

// Round 12
// 160.136 us; speedup vs baseline: 3.4180x; 3.4180x over previous
//
#include <hip/hip_runtime.h>
#include <hip/hip_bf16.h>

#define NTOK   65536
#define KCODES 1024
#define DIM    256
#define LOSS_OFF ((size_t)NTOK * DIM)
#define IDX_OFF  (LOSS_OFF + 1)

#define MARGA 2e-4f     // a-space margin (validated rounds 8/10)

// ---- scratch layout inside the z_q output region (float-slot offsets) ----
#define SC_ZSQ    0              // 65536 f
#define SC_A1     65536          // 65536 f
#define SC_LOSS2  131072         // 65536 f
#define SC_ESQ    196608         // 1024 f
#define SC_ESQNH  197632         // 1024 f
#define SC_PART   198656         // 64 f
#define SC_WCNT   198720         // 1 int
#define SC_WCNT2  198721         // 1 int
#define SC_CNTG   198784         // 65536 int
#define SC_LISTS  264320         // 524288 int (8 per token)
#define SC_WLIST  788608         // 65536 int
#define SC_WLIST2 854144         // 4096 int
#define SC_EHIMG  858240         // 131072 f-slots = 512 KB bf16 emb image
#define SC_ZIMG   989312         // 8388608 f-slots = 32 MB bf16 z image (frag layout)
#define SC_PAIRD  9377920        // 524288 f (per-pair faithful distances)

typedef __attribute__((ext_vector_type(8))) short short8;
typedef __attribute__((ext_vector_type(4))) float f32x4;

__device__ __forceinline__ unsigned f2bf(float x) {
    unsigned u = __float_as_uint(x);
    return (u + 0x7FFFu + ((u >> 16) & 1u)) >> 16;   // RNE
}

__device__ __forceinline__ void gload16(const void* g, void* l) {
    __builtin_amdgcn_global_load_lds((const __attribute__((address_space(1))) unsigned int*)g,
                                     (__attribute__((address_space(3))) unsigned int*)l,
                                     16, 0, 0);
}

// faithful fp32 distance (validated rounds 4-10): sequential single-acc FMA chain
__device__ __forceinline__ float faithful_d(const float* __restrict__ z,
                                            const float* __restrict__ emb,
                                            float zsq, float esq, int tok, int c) {
    const float4* zr = (const float4*)(z + (size_t)tok * DIM);
    const float4* er = (const float4*)(emb + (size_t)c * DIM);
    float acc = 0.f;
#pragma unroll 8
    for (int q = 0; q < 64; ++q) {
        float4 a = zr[q], b = er[q];
        acc = fmaf(a.x, b.x, acc); acc = fmaf(a.y, b.y, acc);
        acc = fmaf(a.z, b.z, acc); acc = fmaf(a.w, b.w, acc);
    }
    float t1 = zsq + esq;
    return t1 - 2.0f * acc;
}

// wave-parallel numpy pairwise sum-of-squares replica (16 lanes per 256-row)
__device__ __forceinline__ float np_rowsq256_wave(const float* row, int sub) {
    const int j = sub & 7, half = sub >> 3;
    const float* a = row + half * 128 + j;
    float r = 0.f;
#pragma unroll
    for (int i = 0; i < 16; ++i) {
        float v = a[i * 8];
        float sq = v * v;
        asm volatile("" : "+v"(sq));
        r += sq;
    }
    float t = r + __shfl_xor(r, 1, 64);
    t = t + __shfl_xor(t, 2, 64);
    t = t + __shfl_xor(t, 4, 64);
    t = t + __shfl_xor(t, 8, 64);
    return t;
}

// ---------------- prep: esq / esqnh (+ worklist counters reset) ----------------
__global__ __launch_bounds__(256) void vq_prep_esq(const float* __restrict__ emb,
                                                   float* __restrict__ esq,
                                                   float* __restrict__ esqnh,
                                                   int* __restrict__ wcnt,
                                                   int* __restrict__ wcnt2) {
    if (blockIdx.x == 0 && threadIdx.x == 0) { *wcnt = 0; *wcnt2 = 0; }
    int code = blockIdx.x * 16 + (threadIdx.x >> 4);   // grid 64
    int sub = threadIdx.x & 15;
    float tot = np_rowsq256_wave(emb + (size_t)code * DIM, sub);
    if (sub == 0) { esq[code] = tot; esqnh[code] = -0.5f * tot; }
}

// ---------------- prep: zsq (np-faithful) + bf16 z image in MFMA-fragment layout ----------------
// (validated round 11) chunk (tok,g): byte = ((bid*4+tf)*8 + (g>>2))*1024 + (((g&3)*16+sl)*16),
// tok = bid*64+tf*16+sl. GEMM lane l reads chunk-row (bid,tf,ks) at byte l*16.
__global__ __launch_bounds__(256) void vq_prep_z(const float* __restrict__ z,
                                                 float* __restrict__ zsq,
                                                 unsigned short* __restrict__ zimg) {
    int tok = blockIdx.x * 16 + (threadIdx.x >> 4);    // grid 4096
    int sub = threadIdx.x & 15;
    float tot = np_rowsq256_wave(z + (size_t)tok * DIM, sub);
    if (sub == 0) zsq[tok] = tot;

    const float* src = z + (size_t)tok * DIM + sub * 16;
    float4 v0 = *(const float4*)&src[0],  v1 = *(const float4*)&src[4];
    float4 v2 = *(const float4*)&src[8],  v3 = *(const float4*)&src[12];
    uint4 p0, p1;
    p0.x = f2bf(v0.x) | (f2bf(v0.y) << 16);  p0.y = f2bf(v0.z) | (f2bf(v0.w) << 16);
    p0.z = f2bf(v1.x) | (f2bf(v1.y) << 16);  p0.w = f2bf(v1.z) | (f2bf(v1.w) << 16);
    p1.x = f2bf(v2.x) | (f2bf(v2.y) << 16);  p1.y = f2bf(v2.z) | (f2bf(v2.w) << 16);
    p1.z = f2bf(v3.x) | (f2bf(v3.y) << 16);  p1.w = f2bf(v3.z) | (f2bf(v3.w) << 16);

    int bid = tok >> 6, tf = (tok >> 4) & 3, sl = tok & 15;
    int g0 = sub * 2, g1 = g0 + 1;
    size_t rowbase = ((size_t)bid * 4 + tf) * 8;
    char* d0 = (char*)zimg + ((rowbase + (g0 >> 2)) << 10) + (((g0 & 3) * 16 + sl) << 4);
    char* d1 = (char*)zimg + ((rowbase + (g1 >> 2)) << 10) + (((g1 & 3) * 16 + sl) << 4);
    *(uint4*)d0 = p0;
    *(uint4*)d1 = p1;
}

// ---------------- prep: bf16 emb image in pre-swizzled LDS slice layout ----------------
__global__ __launch_bounds__(256) void vq_prep_eimg(const float* __restrict__ emb,
                                                    unsigned short* __restrict__ img) {
    int job = blockIdx.x * 256 + threadIdx.x;   // grid 32
    int code = job >> 3, ks = job & 7;
    int cc = (code >> 6) & 3, lcl = (code >> 8) * 64 + (code & 63);
    const float* src = emb + (size_t)code * DIM + ks * 32;
    char* base = (char*)img + (size_t)(cc * 8 + ks) * 16384;
#pragma unroll
    for (int q = 0; q < 4; ++q) {
        float4 v0 = *(const float4*)&src[q * 8];
        float4 v1 = *(const float4*)&src[q * 8 + 4];
        uint4 p;
        p.x = f2bf(v0.x) | (f2bf(v0.y) << 16);
        p.y = f2bf(v0.z) | (f2bf(v0.w) << 16);
        p.z = f2bf(v1.x) | (f2bf(v1.y) << 16);
        p.w = f2bf(v1.z) | (f2bf(v1.w) << 16);
        *(uint4*)(base + lcl * 64 + ((q * 16) ^ (((lcl >> 1) & 3) << 4))) = p;
    }
}

// ---------------- GEMM filter: round-10 barrier-per-step schedule + zf in registers ----------------
template<int PASS>
__global__ __launch_bounds__(256, 2) void vq_gemm(const unsigned short* __restrict__ zimg,
                                                  const unsigned short* __restrict__ img,
                                                  const float* __restrict__ esqnh,
                                                  const float* __restrict__ zsq,
                                                  float* __restrict__ a1,
                                                  int* __restrict__ wcnt,
                                                  int* __restrict__ wlist,
                                                  int* __restrict__ cntg,
                                                  int* __restrict__ listsg,
                                                  float* __restrict__ loss2,
                                                  float* __restrict__ dout) {
    __shared__ __align__(16) short eh_s[2][8192];     // 2 x 16 KB (async-staged e image)
    __shared__ float a1w_s[4][64];
    __shared__ int cnt_s[64];
    __shared__ int lists_s[512];

    const int tid = threadIdx.x, bid = blockIdx.x;
    const int w = tid >> 6, l = tid & 63;
    const int t0 = bid * 64;

    // z fragments -> registers (coalesced 1KB wave loads; layout validated round 11)
    short8 zf[4][8];
#pragma unroll
    for (int tf = 0; tf < 4; ++tf)
#pragma unroll
        for (int ks = 0; ks < 8; ++ks)
            zf[tf][ks] = *(const short8*)((const char*)zimg +
                           ((((size_t)bid * 4 + tf) * 8 + ks) << 10) + (size_t)l * 16);

    if (PASS == 2 && tid < 64) cnt_s[tid] = 0;
    // issue eh slice 0 (async -> eh_s[0])
    {
        const char* gs = (const char*)img + w * 4096 + (size_t)l * 16;
        char* ld = (char*)&eh_s[0][0] + w * 4096;
#pragma unroll
        for (int i = 0; i < 4; ++i) gload16(gs + i * 1024, ld + i * 1024);
    }
    __syncthreads();

    float thrv[4], amax[4];
#pragma unroll
    for (int tf = 0; tf < 4; ++tf) {
        amax[tf] = -3.4e38f;
        if (PASS == 2) thrv[tf] = a1[t0 + tf * 16 + (l & 15)] - MARGA;
    }

    f32x4 acc[4][4];

#pragma unroll
    for (int c = 0; c < 4; ++c) {
#pragma unroll
        for (int f = 0; f < 4; ++f) {
            f32x4 e4 = *(const f32x4*)&esqnh[w * 256 + c * 64 + f * 16 + (l >> 4) * 4];
#pragma unroll
            for (int tf = 0; tf < 4; ++tf) acc[f][tf] = e4;
        }
#pragma unroll
        for (int ks = 0; ks < 8; ++ks) {
            int s = c * 8 + ks, buf = s & 1;
            if (s < 31) {   // prefetch next slice async into other buffer
                const char* gs = (const char*)img + (size_t)(s + 1) * 16384 + w * 4096 + (size_t)l * 16;
                char* ld = (char*)&eh_s[buf ^ 1][0] + w * 4096;
#pragma unroll
                for (int i = 0; i < 4; ++i) gload16(gs + i * 1024, ld + i * 1024);
            }
            short8 afr[4];
#pragma unroll
            for (int f = 0; f < 4; ++f) {
                int lcl = w * 64 + f * 16 + (l & 15);
                int byte = lcl * 64 + (((l >> 4) * 16) ^ (((lcl >> 1) & 3) << 4));
                afr[f] = *(const short8*)((const char*)&eh_s[buf][0] + byte);
            }
#pragma unroll
            for (int f = 0; f < 4; ++f)
#pragma unroll
                for (int tf = 0; tf < 4; ++tf)
                    acc[f][tf] = __builtin_amdgcn_mfma_f32_16x16x32_bf16(
                        afr[f], zf[tf][ks], acc[f][tf], 0, 0, 0);
            __syncthreads();   // drains prefetch + buffer swap (validated round-10 schedule)
        }
        if (PASS == 1) {
#pragma unroll
            for (int tf = 0; tf < 4; ++tf) {
                float m0 = fmaxf(fmaxf(acc[0][tf][0], acc[0][tf][1]), fmaxf(acc[0][tf][2], acc[0][tf][3]));
                float m1 = fmaxf(fmaxf(acc[1][tf][0], acc[1][tf][1]), fmaxf(acc[1][tf][2], acc[1][tf][3]));
                float m2 = fmaxf(fmaxf(acc[2][tf][0], acc[2][tf][1]), fmaxf(acc[2][tf][2], acc[2][tf][3]));
                float m3 = fmaxf(fmaxf(acc[3][tf][0], acc[3][tf][1]), fmaxf(acc[3][tf][2], acc[3][tf][3]));
                amax[tf] = fmaxf(amax[tf], fmaxf(fmaxf(m0, m1), fmaxf(m2, m3)));
            }
        } else {
#pragma unroll
            for (int tf = 0; tf < 4; ++tf) {
                int tokl = tf * 16 + (l & 15);
#pragma unroll
                for (int f = 0; f < 4; ++f)
#pragma unroll
                    for (int r = 0; r < 4; ++r) {
                        float a = acc[f][tf][r];
                        if (a >= thrv[tf]) {
                            int code = w * 256 + c * 64 + f * 16 + (l >> 4) * 4 + r;
                            int pos = atomicAdd(&cnt_s[tokl], 1);
                            if (pos < 8) lists_s[tokl * 8 + pos] = code;
                        }
                    }
            }
        }
    }

    if (PASS == 1) {
#pragma unroll
        for (int tf = 0; tf < 4; ++tf) {
            float m = amax[tf];
            m = fmaxf(m, __shfl_xor(m, 16, 64));
            m = fmaxf(m, __shfl_xor(m, 32, 64));
            if (l < 16) a1w_s[w][tf * 16 + l] = m;
        }
        __syncthreads();
        if (tid < 64)
            a1[t0 + tid] = fmaxf(fmaxf(a1w_s[0][tid], a1w_s[1][tid]),
                                 fmaxf(a1w_s[2][tid], a1w_s[3][tid]));
    } else {
        __syncthreads();
        if (tid < 64) {
            int t = t0 + tid, ct = cnt_s[tid];
            if (ct == 1) {
                dout[IDX_OFF + t] = (float)lists_s[tid * 8];
                loss2[t] = fmaf(-2.f, a1[t], zsq[t]);
            } else {
                int pos = atomicAdd(wcnt, 1);
                wlist[pos] = t;
                cntg[t] = ct;
                int m = ct < 8 ? ct : 8;
                for (int i = 0; i < m; ++i) listsg[t * 8 + i] = lists_s[tid * 8 + i];
            }
        }
    }
}

// ---------------- pairs: one LANE per (hard-token, candidate) pair ----------------
__global__ __launch_bounds__(256) void vq_pairs(const float* __restrict__ z,
                                                const float* __restrict__ emb,
                                                const float* __restrict__ zsq,
                                                const float* __restrict__ esq,
                                                const int* __restrict__ wcnt,
                                                const int* __restrict__ wlist,
                                                const int* __restrict__ cntg,
                                                const int* __restrict__ listsg,
                                                int* __restrict__ wcnt2,
                                                int* __restrict__ wlist2,
                                                float* __restrict__ paird) {
    const int n = wcnt[0];
    const int total = 8 * n;
    for (int p = blockIdx.x * 256 + threadIdx.x; p < total; p += 2048 * 256) {
        int q = p >> 3, slot = p & 7;
        int tok = wlist[q];
        int ct = cntg[tok];
        if (ct == 0 || ct > 8) {
            if (slot == 0) {
                int pos = atomicAdd(wcnt2, 1);
                if (pos < 4096) wlist2[pos] = tok;
            }
            continue;
        }
        if (slot >= ct) continue;
        int code = listsg[tok * 8 + slot];
        paird[p] = faithful_d(z, emb, zsq[tok], esq[code], tok, code);
    }
}

// ---------------- pick: thread per hard token, lexicographic (d, code) argmin ----------------
__global__ __launch_bounds__(256) void vq_pick(const float* __restrict__ paird,
                                               const int* __restrict__ wcnt,
                                               const int* __restrict__ wlist,
                                               const int* __restrict__ cntg,
                                               const int* __restrict__ listsg,
                                               float* __restrict__ loss2,
                                               float* __restrict__ dout) {
    const int n = wcnt[0];
    for (int q = blockIdx.x * 256 + threadIdx.x; q < n; q += 256 * 256) {
        int tok = wlist[q];
        int ct = cntg[tok];
        if (ct == 0 || ct > 8) continue;   // scan kernel owns these
        float db = paird[q * 8];
        int cb = listsg[tok * 8];
        for (int i = 1; i < ct; ++i) {
            float d = paird[q * 8 + i];
            int c = listsg[tok * 8 + i];
            if (d < db || (d == db && c < cb)) { db = d; cb = c; }
        }
        dout[IDX_OFF + tok] = (float)cb;
        loss2[tok] = db;
    }
}

// ---------------- decide (scan): BLOCK per token, full 1024 faithful scan (rare) ----------------
__global__ __launch_bounds__(256) void vq_decide_scan(const float* __restrict__ z,
                                                      const float* __restrict__ emb,
                                                      const float* __restrict__ zsq,
                                                      const float* __restrict__ esq,
                                                      const int* __restrict__ wcnt2,
                                                      const int* __restrict__ wlist2,
                                                      float* __restrict__ loss2,
                                                      float* __restrict__ dout) {
    __shared__ __align__(16) float zrow[DIM];
    __shared__ float dred[256];
    __shared__ int   ired[256];
    int n = wcnt2[0];
    if (n > 4096) n = 4096;
    const int tid = threadIdx.x;
    for (int job = blockIdx.x; job < n; job += 128) {
        int tok = wlist2[job];
        __syncthreads();
        if (tid < 64) ((float4*)zrow)[tid] = ((const float4*)(z + (size_t)tok * DIM))[tid];
        __syncthreads();
        float zq = zsq[tok];
        float a0 = 0.f, a1v = 0.f, a2 = 0.f, a3 = 0.f;
        const float4* e0 = (const float4*)(emb + (size_t)(tid      ) * DIM);
        const float4* e1 = (const float4*)(emb + (size_t)(tid + 256) * DIM);
        const float4* e2 = (const float4*)(emb + (size_t)(tid + 512) * DIM);
        const float4* e3 = (const float4*)(emb + (size_t)(tid + 768) * DIM);
#pragma unroll
        for (int seg = 0; seg < 4; ++seg) {
#pragma unroll
            for (int qq = 0; qq < 16; ++qq) {
                float4 a = ((float4*)zrow)[seg * 16 + qq];
                float4 b0 = e0[seg * 16 + qq], b1 = e1[seg * 16 + qq];
                float4 b2 = e2[seg * 16 + qq], b3 = e3[seg * 16 + qq];
                a0 = fmaf(a.x, b0.x, a0); a0 = fmaf(a.y, b0.y, a0);
                a0 = fmaf(a.z, b0.z, a0); a0 = fmaf(a.w, b0.w, a0);
                a1v = fmaf(a.x, b1.x, a1v); a1v = fmaf(a.y, b1.y, a1v);
                a1v = fmaf(a.z, b1.z, a1v); a1v = fmaf(a.w, b1.w, a1v);
                a2 = fmaf(a.x, b2.x, a2); a2 = fmaf(a.y, b2.y, a2);
                a2 = fmaf(a.z, b2.z, a2); a2 = fmaf(a.w, b2.w, a2);
                a3 = fmaf(a.x, b3.x, a3); a3 = fmaf(a.y, b3.y, a3);
                a3 = fmaf(a.z, b3.z, a3); a3 = fmaf(a.w, b3.w, a3);
            }
        }
        float d0 = (zq + esq[tid      ]) - 2.0f * a0;
        float d1 = (zq + esq[tid + 256]) - 2.0f * a1v;
        float d2 = (zq + esq[tid + 512]) - 2.0f * a2;
        float d3 = (zq + esq[tid + 768]) - 2.0f * a3;
        float db = d0; int cb = tid;
        if (d1 < db) { db = d1; cb = tid + 256; }
        if (d2 < db) { db = d2; cb = tid + 512; }
        if (d3 < db) { db = d3; cb = tid + 768; }
        dred[tid] = db; ired[tid] = cb;
        __syncthreads();
        for (int step = 128; step >= 1; step >>= 1) {
            if (tid < step) {
                float od = dred[tid + step]; int oi = ired[tid + step];
                if (od < dred[tid] || (od == dred[tid] && oi < ired[tid])) {
                    dred[tid] = od; ired[tid] = oi;
                }
            }
            __syncthreads();
        }
        if (tid == 0) {
            dout[IDX_OFF + tok] = (float)ired[0];
            loss2[tok] = dred[0];
        }
    }
}

// ---------------- loss reduction (fixed order) ----------------
__global__ __launch_bounds__(256) void vq_sum(const float* __restrict__ loss2,
                                              float* __restrict__ part) {
    __shared__ float ws[4];
    float s = 0.f;
#pragma unroll
    for (int q = 0; q < 4; ++q)
        s += loss2[blockIdx.x * 1024 + q * 256 + threadIdx.x];
#pragma unroll
    for (int m = 1; m < 64; m <<= 1) s += __shfl_xor(s, m, 64);
    if ((threadIdx.x & 63) == 0) ws[threadIdx.x >> 6] = s;
    __syncthreads();
    if (threadIdx.x == 0) part[blockIdx.x] = ws[0] + ws[1] + ws[2] + ws[3];
}

__global__ __launch_bounds__(64) void vq_final(const float* __restrict__ part,
                                               float* __restrict__ dout) {
    double s = (double)part[threadIdx.x];
#pragma unroll
    for (int m = 1; m < 64; m <<= 1) s += __shfl_xor(s, m, 64);
    if (threadIdx.x == 0) dout[LOSS_OFF] = (float)(s * 1.25 / 16777216.0);
}

// ---------------- gather z_q rows ----------------
__global__ __launch_bounds__(256) void vq_gather(const float* __restrict__ emb,
                                                 float* __restrict__ dout) {
    const int w = threadIdx.x >> 6, l = threadIdx.x & 63;
    for (int tok = blockIdx.x * 4 + w; tok < NTOK; tok += 2048 * 4) {
        int widx = (int)dout[IDX_OFF + tok];
        float4 ev = *(const float4*)&emb[(size_t)widx * DIM + l * 4];
        *(float4*)&dout[(size_t)tok * DIM + l * 4] = ev;
    }
}

extern "C" void kernel_launch(void* const* d_in, const int* in_sizes, int n_in,
                              void* d_out, int out_size, void* d_ws, size_t ws_size,
                              hipStream_t stream) {
    const float* z   = (const float*)d_in[0];
    const float* emb = (const float*)d_in[1];
    float* out = (float*)d_out;

    float* zsq   = out + SC_ZSQ;
    float* a1    = out + SC_A1;
    float* loss2 = out + SC_LOSS2;
    float* esq   = out + SC_ESQ;
    float* esqnh = out + SC_ESQNH;
    float* part  = out + SC_PART;
    int*   wcnt  = (int*)(out + SC_WCNT);
    int*   wcnt2 = (int*)(out + SC_WCNT2);
    int*   cntg  = (int*)(out + SC_CNTG);
    int*   listsg= (int*)(out + SC_LISTS);
    int*   wlist = (int*)(out + SC_WLIST);
    int*   wlist2= (int*)(out + SC_WLIST2);
    float* paird = out + SC_PAIRD;
    unsigned short* img  = (unsigned short*)(out + SC_EHIMG);
    unsigned short* zimg = (unsigned short*)(out + SC_ZIMG);

    vq_prep_esq <<<64,   256, 0, stream>>>(emb, esq, esqnh, wcnt, wcnt2);
    vq_prep_z   <<<4096, 256, 0, stream>>>(z, zsq, zimg);
    vq_prep_eimg<<<32,   256, 0, stream>>>(emb, img);
    vq_gemm<1>  <<<1024, 256, 0, stream>>>(zimg, img, esqnh, zsq, a1, wcnt, wlist, cntg, listsg, loss2, out);
    vq_gemm<2>  <<<1024, 256, 0, stream>>>(zimg, img, esqnh, zsq, a1, wcnt, wlist, cntg, listsg, loss2, out);
    vq_pairs    <<<2048, 256, 0, stream>>>(z, emb, zsq, esq, wcnt, wlist, cntg, listsg, wcnt2, wlist2, paird);
    vq_pick     <<<256,  256, 0, stream>>>(paird, wcnt, wlist, cntg, listsg, loss2, out);
    vq_decide_scan<<<128, 256, 0, stream>>>(z, emb, zsq, esq, wcnt2, wlist2, loss2, out);
    vq_sum      <<<64,   256, 0, stream>>>(loss2, part);
    vq_final    <<<1,    64,  0, stream>>>(part, out);
    vq_gather   <<<2048, 256, 0, stream>>>(emb, out);
}